// Round 14
// baseline (107.744 us; speedup 1.0000x reference)
//
#include <hip/hip_runtime.h>
#include <math.h>

#define NF 1024
#define DIM 256
#define BATCH 2048
#define K 512              // interleaved (x^2, x) -> 2*DIM
#define BMF 64             // batch rows per fused block (L1-reuse probe)
#define KS 32              // k elems per step
#define NSTEP (K / KS)     // 16

// ws layout (unchanged from r9/r13):
//   [0, 1MB)    : Bb bf16 [NSTEP][4(q)][NF][8]
//   [1MB, +4KB) : c  float[NF]
#define WS_C_OFF (NF * K * 2)

typedef __attribute__((ext_vector_type(8))) short short8;   // 8 bf16
typedef __attribute__((ext_vector_type(4))) float f32x4;    // MFMA acc

__device__ __forceinline__ unsigned short f2bf(float f) {
    unsigned u = __float_as_uint(f);
    u += 0x7fffu + ((u >> 16) & 1u);       // RNE
    return (unsigned short)(u >> 16);
}

// ---------------------------------------------------------------------------
// K1: unchanged (q-major step-major Bb + c).
__global__ __launch_bounds__(256) void k_prep(const float* __restrict__ mu,
                                              const float* __restrict__ sigma,
                                              uint4* __restrict__ Bb4,
                                              float* __restrict__ c) {
    const int t = threadIdx.x;
    const int f = blockIdx.x * 4 + (t >> 6);
    const int sq = t & 63;                 // s = sq>>2, q = sq&3
    const float4 mv = *(const float4*)&mu[f * DIM + sq * 4];
    const float4 sv = *(const float4*)&sigma[f * DIM + sq * 4];

    uint4 pk; float cp = 0.f;
    {
        const float s2x = sv.x * sv.x;
        pk.x = (unsigned)f2bf(s2x) | ((unsigned)f2bf(-2.0f * s2x * mv.x) << 16);
        cp += s2x * mv.x * mv.x;
        const float s2y = sv.y * sv.y;
        pk.y = (unsigned)f2bf(s2y) | ((unsigned)f2bf(-2.0f * s2y * mv.y) << 16);
        cp += s2y * mv.y * mv.y;
        const float s2z = sv.z * sv.z;
        pk.z = (unsigned)f2bf(s2z) | ((unsigned)f2bf(-2.0f * s2z * mv.z) << 16);
        cp += s2z * mv.z * mv.z;
        const float s2w = sv.w * sv.w;
        pk.w = (unsigned)f2bf(s2w) | ((unsigned)f2bf(-2.0f * s2w * mv.w) << 16);
        cp += s2w * mv.w * mv.w;
    }
    // uint4 index: s*4096 + q*1024 + f
    Bb4[(sq >> 2) * 4096 + (sq & 3) * 1024 + f] = pk;

    #pragma unroll
    for (int off = 32; off > 0; off >>= 1) cp += __shfl_down(cp, off, 64);
    if ((t & 63) == 0) c[f] = cp;
}

// ---------------------------------------------------------------------------
// K2: fused GEMM + epilogue + full-row softmax; L1-REUSE GEOMETRY.
// 32 blocks x 1024 threads. Block = 64 rows x ALL 1024 formulas. Waves as
// 4M x 4N: wave (mw,nw) computes rows [mw*16,+16) x formulas [nw*256,+256)
// as 16 ct tiles. The 4 waves of each N-group read the SAME B bytes
// (16 KB/step, L1-resident) -> x4 L1 hit potential on the dominant stream.
//   A (64x512 bf16, 64 KB): XOR-swizzled LDS, shared by all 16 waves.
//   B: global->reg, 4-deep ct-level ring (static indices), barrier-free.
__global__ __launch_bounds__(1024, 1) void k_fused(const float* __restrict__ x,
                                                   const ushort* __restrict__ Bb,
                                                   const float* __restrict__ c,
                                                   const float* __restrict__ temp,
                                                   float* __restrict__ out) {
    const int t = threadIdx.x;
    const int w = t >> 6;          // wave 0..15
    const int lane = t & 63;
    const int m16 = lane & 15;
    const int q = lane >> 4;       // 0..3
    const int mw = w >> 2, nw = w & 3;
    const int r0 = blockIdx.x * BMF;

    __shared__ __align__(16) ushort ldsA[BMF * K];      // 64 KB, swizzled
    __shared__ float wsum[16][16];
    __shared__ float rowInv[BMF];

    // ---- pack A: 4096 units of 16B, 4 per thread ----
    #pragma unroll
    for (int h = 0; h < 4; ++h) {
        const int u = h * 1024 + t;
        const int row = u >> 6, kc = u & 63;
        const float4 v = *(const float4*)&x[(r0 + row) * DIM + kc * 4];
        uint4 pk;
        pk.x = (unsigned)f2bf(v.x * v.x) | ((unsigned)f2bf(v.x) << 16);
        pk.y = (unsigned)f2bf(v.y * v.y) | ((unsigned)f2bf(v.y) << 16);
        pk.z = (unsigned)f2bf(v.z * v.z) | ((unsigned)f2bf(v.z) << 16);
        pk.w = (unsigned)f2bf(v.w * v.w) | ((unsigned)f2bf(v.w) << 16);
        *(uint4*)&ldsA[(row * 64 + (kc ^ (row & 7))) * 8] = pk;
    }

    f32x4 acc[16];
    #pragma unroll
    for (int ct = 0; ct < 16; ++ct) acc[ct] = (f32x4){0.f, 0.f, 0.f, 0.f};

    // per-lane B base: q-slot, N-group nw, formula-in-tile m16.
    // ct tile -> +ct*128 elems; step s -> +s*NF*KS elems.
    const ushort* bp = Bb + q * (NF * 8) + nw * 2048 + m16 * 8;
    const int ar = mw * 16 + m16;          // A row for this lane

    // ring-4 prologue: tiles (s=0, ct=0..3)
    short8 bv[4];
    #pragma unroll
    for (int ct = 0; ct < 4; ++ct)
        bv[ct] = *(const short8*)(bp + ct * 128);

    __syncthreads();   // ldsA ready (only pre-epilogue barrier)

    // ---- K loop: barrier-free; ring-4 ct pipeline; loads stop at u=251 ----
    #pragma unroll 1
    for (int s = 0; s < NSTEP - 1; ++s) {
        const int kcq = s * 4 + q;
        const short8 av = *(const short8*)&ldsA[(ar * 64 + (kcq ^ (ar & 7))) * 8];
        #pragma unroll
        for (int ct = 0; ct < 16; ++ct) {
            acc[ct] = __builtin_amdgcn_mfma_f32_16x16x32_bf16(av, bv[ct & 3], acc[ct], 0, 0, 0);
            const int ns  = (ct < 12) ? s : s + 1;       // refill slot ct&3
            const int nct = (ct < 12) ? ct + 4 : ct - 12;
            bv[ct & 3] = *(const short8*)(bp + ns * (NF * KS) + nct * 128);
        }
    }
    {   // peeled last step s = 15: load only for ct<12
        const int kcq = (NSTEP - 1) * 4 + q;
        const short8 av = *(const short8*)&ldsA[(ar * 64 + (kcq ^ (ar & 7))) * 8];
        #pragma unroll
        for (int ct = 0; ct < 16; ++ct) {
            acc[ct] = __builtin_amdgcn_mfma_f32_16x16x32_bf16(av, bv[ct & 3], acc[ct], 0, 0, 0);
            if (ct < 12)
                bv[ct & 3] = *(const short8*)(bp + (NSTEP - 1) * (NF * KS) + (ct + 4) * 128);
        }
    }

    // ---- epilogue: p = exp(g*exp(-dist)) in registers; wave row-sums ----
    const float g = 1.0f / (1.0f + __expf(-temp[0]));
    float s4[4] = {0.f, 0.f, 0.f, 0.f};
    #pragma unroll
    for (int ct = 0; ct < 16; ++ct) {
        const float cn = c[nw * 256 + ct * 16 + m16];
        #pragma unroll
        for (int i = 0; i < 4; ++i) {
            const float dist2 = acc[ct][i] + cn;
            const float dist = sqrtf(fmaxf(dist2, 0.0f));
            const float p = __expf(g * __expf(-dist));
            acc[ct][i] = p;
            s4[i] += p;
        }
    }
    #pragma unroll
    for (int i = 0; i < 4; ++i) {
        #pragma unroll
        for (int mask = 1; mask < 16; mask <<= 1)
            s4[i] += __shfl_xor(s4[i], mask, 64);
    }
    if (m16 == 0) {
        #pragma unroll
        for (int i = 0; i < 4; ++i) wsum[w][q * 4 + i] = s4[i];
    }
    __syncthreads();
    if (t < BMF) {                      // row t: mw=t>>4, r16=t&15
        const int b = (t >> 4) * 4, r16 = t & 15;
        const float ssum = (wsum[b][r16] + wsum[b + 1][r16]) +
                           (wsum[b + 2][r16] + wsum[b + 3][r16]);
        rowInv[t] = 1.0f / ssum;
    }
    __syncthreads();

    // ---- normalize in-register p, single out write ----
    float inv[4];
    #pragma unroll
    for (int i = 0; i < 4; ++i) inv[i] = rowInv[mw * 16 + q * 4 + i];
    #pragma unroll
    for (int ct = 0; ct < 16; ++ct) {
        const int fcol = nw * 256 + ct * 16 + m16;
        #pragma unroll
        for (int i = 0; i < 4; ++i)
            out[(r0 + mw * 16 + q * 4 + i) * NF + fcol] = acc[ct][i] * inv[i];
    }
}

extern "C" void kernel_launch(void* const* d_in, const int* in_sizes, int n_in,
                              void* d_out, int out_size, void* d_ws, size_t ws_size,
                              hipStream_t stream) {
    const float* x     = (const float*)d_in[0];
    const float* mu    = (const float*)d_in[1];
    const float* sigma = (const float*)d_in[2];
    const float* temp  = (const float*)d_in[3];
    float* out = (float*)d_out;

    char* ws = (char*)d_ws;
    ushort* Bb = (ushort*)ws;
    float*  c  = (float*)(ws + WS_C_OFF);

    k_prep<<<NF / 4, 256, 0, stream>>>(mu, sigma, (uint4*)Bb, c);
    k_fused<<<BATCH / BMF, 1024, 0, stream>>>(x, Bb, c, temp, out);
}